// Round 5
// baseline (554.656 us; speedup 1.0000x reference)
//
#include <hip/hip_runtime.h>
#include <hip/hip_bf16.h>
#include <cstdint>
#include <cstddef>

#define BN_EPS 1e-5f

typedef short short8 __attribute__((ext_vector_type(8)));
typedef float float16 __attribute__((ext_vector_type(16)));
typedef unsigned short ushort_t;

__device__ __forceinline__ float bf2f(ushort_t u) {
  return __uint_as_float(((unsigned int)u) << 16);
}
__device__ __forceinline__ ushort_t f2bf(float f) {
  unsigned int u = __float_as_uint(f);
  u += 0x7FFFu + ((u >> 16) & 1u);
  return (ushort_t)(u >> 16);
}

// async global->LDS DMA, 16 B per lane; LDS dest = wave-uniform base + lane*16
__device__ __forceinline__ void dma16(const void* g, const void* l) {
  typedef const __attribute__((address_space(1))) unsigned int* gp_t;
  typedef __attribute__((address_space(3))) unsigned int* lp_t;
  __builtin_amdgcn_global_load_lds((gp_t)(uintptr_t)g,
                                   (lp_t)(unsigned int)(uintptr_t)l, 16, 0, 0);
}

// channel swizzle applied at PRODUCER side so linear DMA staging yields
// bank-conflict-free LDS: group g of chunk stored at slot g ^ ((xp>>1)&3)
__device__ __forceinline__ int swz_c(int c, int xp) {
  int cc = c >> 5;
  int g = (c >> 3) & 3;
  return cc * 32 + ((g ^ ((xp >> 1) & 3)) << 3) + (c & 7);
}

// ------------------------------------------------------------------
// PFN (fp32)
// ------------------------------------------------------------------

__global__ __launch_bounds__(256) void pfn_stats(
    const float* __restrict__ pillars, const float* __restrict__ lin_w,
    const float* __restrict__ lin_b, float* __restrict__ acc) {
  __shared__ float s_p[288];
  __shared__ float red[512];
  int tid = threadIdx.x;
  int c = tid & 63, rs = tid >> 6;
  float w[9];
#pragma unroll
  for (int d = 0; d < 9; ++d) w[d] = lin_w[c * 9 + d];
  float bl = lin_b[c];
  float s = 0.f, s2 = 0.f;
  long base_row = (long)blockIdx.x * 1024;
  for (int ch = 0; ch < 32; ++ch) {
    long crow = base_row + ch * 32;
    __syncthreads();
    for (int i = tid; i < 288; i += 256) s_p[i] = pillars[crow * 9 + i];
    __syncthreads();
#pragma unroll
    for (int k = 0; k < 8; ++k) {
      const float* pr = &s_p[(rs * 8 + k) * 9];
      float y = bl;
#pragma unroll
      for (int d = 0; d < 9; ++d) y += pr[d] * w[d];
      s += y;
      s2 += y * y;
    }
  }
  red[tid] = s;
  red[tid + 256] = s2;
  __syncthreads();
  if (rs == 0) {
    float ts = red[c] + red[c + 64] + red[c + 128] + red[c + 192];
    float t2 = red[256 + c] + red[256 + c + 64] + red[256 + c + 128] + red[256 + c + 192];
    atomicAdd(&acc[c], ts);
    atomicAdd(&acc[c + 64], t2);
  }
}

__global__ void pfn_finalize(const float* __restrict__ acc, const float* __restrict__ g,
                             const float* __restrict__ b, float* __restrict__ ss) {
  int c = threadIdx.x;  // 64 threads
  const float invN = 1.f / 640000.f;
  float m = acc[c] * invN;
  float v = acc[c + 64] * invN - m * m;
  v = fmaxf(v, 0.f);
  float inv = rsqrtf(v + BN_EPS);
  float sc = g[c] * inv;
  ss[c] = sc;
  ss[c + 64] = b[c] - m * sc;
}

__global__ __launch_bounds__(256) void pfn_feats(
    const float* __restrict__ pillars, const float* __restrict__ lin_w,
    const float* __restrict__ lin_b, const float* __restrict__ ss,
    float* __restrict__ feats) {
  __shared__ float s_p[1152];
  int tid = threadIdx.x;
  int c = tid & 63, pe = tid >> 6;
  long pb = (long)blockIdx.x * 4;
  for (int i = tid; i < 1152; i += 256) s_p[i] = pillars[pb * 288 + i];
  float w[9];
#pragma unroll
  for (int d = 0; d < 9; ++d) w[d] = lin_w[c * 9 + d];
  float bl = lin_b[c];
  float sc = ss[c], sh = ss[c + 64];
  __syncthreads();
  const float* pp = &s_p[pe * 288];
  float m = -1e30f;
#pragma unroll 4
  for (int n = 0; n < 32; ++n) {
    float y = bl;
#pragma unroll
    for (int d = 0; d < 9; ++d) y += pp[n * 9 + d] * w[d];
    float v = fmaxf(y * sc + sh, 0.f);
    m = fmaxf(m, v);
  }
  feats[(pb + pe) * 64 + c] = m;
}

// ------------------------------------------------------------------
// Scatter into padded bf16 HWC canvas (numpy last-write-wins), swizzled
// ------------------------------------------------------------------

__global__ void scatter_winner(const int* __restrict__ coords, int* __restrict__ winner,
                               int P) {
  int p = blockIdx.x * 256 + threadIdx.x;
  if (p >= P) return;
  int y = coords[p * 3 + 1], x = coords[p * 3 + 2];
  if (y >= 0 && y < 666 && x >= 0 && x < 666) atomicMax(&winner[y * 666 + x], p);
}

__global__ void scatter_img(const int* __restrict__ coords, const int* __restrict__ winner,
                            const float* __restrict__ feats, ushort_t* __restrict__ img,
                            int P, int PW) {
  int idx = blockIdx.x * 256 + threadIdx.x;
  int p = idx >> 6, c = idx & 63;
  if (p >= P) return;
  int y = coords[p * 3 + 1], x = coords[p * 3 + 2];
  if (y >= 0 && y < 666 && x >= 0 && x < 666) {
    if (winner[y * 666 + x] == p) {
      int xp = x + 1;
      img[((size_t)(y + 1) * PW + xp) * 64 + swz_c(c, xp)] = f2bf(feats[p * 64 + c]);
    }
  }
}

// ------------------------------------------------------------------
// Weight prep: OIHW fp32 -> fragment-ordered bf16.
// layout: [cc32][pos][ks(2)][ntg][lane 64][8]
//   lane l: n = ntg*32 + (l&31); c = cc*32 + ks*16 + (l>>5)*8 + j
// ------------------------------------------------------------------

__global__ void prep_w(const float* __restrict__ w, ushort_t* __restrict__ w2, int C,
                       int N, int Ntg, int chunks) {
  int u = blockIdx.x * 256 + threadIdx.x;
  int total = chunks * 9 * 2 * Ntg * 64;
  if (u >= total) return;
  int l = u & 63;
  int g = u >> 6;
  int ntg = g % Ntg;
  g /= Ntg;
  int ks = g & 1;
  g >>= 1;
  int pos = g % 9;
  int cc = g / 9;
  int n = ntg * 32 + (l & 31);
  int c0 = cc * 32 + ks * 16 + (l >> 5) * 8;
  ushort_t o8[8];
#pragma unroll
  for (int j = 0; j < 8; ++j) {
    int c = c0 + j;
    float v = (n < N && c < C) ? w[((size_t)n * C + c) * 9 + pos] : 0.f;
    o8[j] = f2bf(v);
  }
  *(uint4*)&w2[(size_t)u * 8] = *(const uint4*)o8;
}

// merged heads: n<21 -> hb_w, 21..23 -> hc_w, >=24 -> 0.  C=256, Ntg=1, chunks=8
__global__ void prep_w_head(const float* __restrict__ hb, const float* __restrict__ hc,
                            ushort_t* __restrict__ w2) {
  int u = blockIdx.x * 256 + threadIdx.x;
  int total = 8 * 9 * 2 * 64;
  if (u >= total) return;
  int l = u & 63;
  int g = u >> 6;
  int ks = g & 1;
  g >>= 1;
  int pos = g % 9;
  int cc = g / 9;
  int n = l & 31;
  int c0 = cc * 32 + ks * 16 + (l >> 5) * 8;
  ushort_t o8[8];
#pragma unroll
  for (int j = 0; j < 8; ++j) {
    int c = c0 + j;
    float v = 0.f;
    if (n < 21) v = hb[((size_t)n * 256 + c) * 9 + pos];
    else if (n < 24) v = hc[((size_t)(n - 21) * 256 + c) * 9 + pos];
    o8[j] = f2bf(v);
  }
  *(uint4*)&w2[(size_t)u * 8] = *(const uint4*)o8;
}

// ------------------------------------------------------------------
// Implicit-GEMM 3x3 conv via v_mfma_f32_32x32x16_bf16, K-chunk = 32.
// Block = 8 waves (512 thr). Tile 64 px x 8 rows, NT*32 oc per block.
// Staging via global_load_lds width-16 DMA (linear LDS, producer-swizzled).
// LDS: s_in 10x66x32ch = 42240 B + s_w 9*2*NT*512*2 B -> 79104 B (NT=2)
//   -> 2 blocks/CU = 16 waves/CU.
// HEAD: blockIdx.z = K-split (cc0 = z); fp32 atomicAdd epilogue.
// ------------------------------------------------------------------

template <int NT, bool HEAD, bool STATS>
__global__ __launch_bounds__(512, 4) void conv_mfma(
    const ushort_t* __restrict__ in, const ushort_t* __restrict__ w2,
    const float* __restrict__ bias, const float* __restrict__ bias2,
    ushort_t* __restrict__ obf, float* __restrict__ oba, float* __restrict__ obb,
    float* __restrict__ statacc, int PW, int W, int H, int C, int nchunks, int Ntg) {
  __shared__ ushort_t s_in[2640 * 8];          // 42240 B
  __shared__ ushort_t s_w[9 * 2 * NT * 512];   // 18432*NT B
  const int tid = threadIdx.x;
  const int lane = tid & 63, wv = tid >> 6;
  const int lc = lane & 31, lh = lane >> 5;
  const int x0 = blockIdx.x * 64, y0 = blockIdx.y * 8;
  const int z = blockIdx.z;
  const int cc0 = HEAD ? z * nchunks : 0;
  const int z_oc = HEAD ? 0 : z;

  // ---- precompute DMA descriptors ----
  int ioffel[6];
  unsigned imask = 0;
  {
    int bu = wv * 64 + lane;
#pragma unroll
    for (int it = 0; it < 6; ++it) {
      int u = bu + it * 512;
      if (u < 2640) {
        int r = u / 264;
        int rem = u - r * 264;
        int col = rem >> 2, h = rem & 3;
        ioffel[it] = (r * PW + col) * C + h * 8;
        imask |= (1u << it);
      } else {
        ioffel[it] = 0;
      }
    }
  }
  constexpr int NSLAB = 9 * 2 * NT;
  constexpr int NB = (NSLAB + 7) / 8;
  int wgoffel[NB];
  unsigned wmask = 0;
#pragma unroll
  for (int it = 0; it < NB; ++it) {
    int q = it * 8 + wv;
    if (q < NSLAB) {
      int nt = q % NT;
      int t = q / NT;
      int ks = t & 1, pos = t >> 1;
      wgoffel[it] = ((pos * 2 + ks) * Ntg + z_oc * NT + nt) * 512 + lane * 8;
      wmask |= (1u << it);
    } else {
      wgoffel[it] = 0;
    }
  }

  float bv[NT];
#pragma unroll
  for (int nt = 0; nt < NT; ++nt) {
    if (HEAD) {
      bv[nt] = (z == 0) ? (lc < 21 ? bias[lc] : (lc < 24 ? bias2[lc - 21] : 0.f)) : 0.f;
    } else {
      bv[nt] = bias[(z * NT + nt) * 32 + lc];
    }
  }
  float16 acc[2][NT];
#pragma unroll
  for (int Mt = 0; Mt < 2; ++Mt)
#pragma unroll
    for (int nt = 0; nt < NT; ++nt)
#pragma unroll
      for (int r = 0; r < 16; ++r) acc[Mt][nt][r] = bv[nt];

  const ushort_t* inb = in + ((size_t)y0 * PW + x0) * C;
  const int stepW = Ntg * 9216;

  for (int cc = 0; cc < nchunks; ++cc) {
    const int ccg = cc0 + cc;
    __syncthreads();
    const ushort_t* ib = inb + ccg * 32;
#pragma unroll
    for (int it = 0; it < 6; ++it)
      if (imask & (1u << it)) dma16(ib + ioffel[it], &s_in[(wv * 64 + it * 512) * 8]);
    const ushort_t* wb = w2 + (size_t)ccg * stepW;
#pragma unroll
    for (int it = 0; it < NB; ++it)
      if (wmask & (1u << it)) dma16(wb + wgoffel[it], &s_w[(it * 8 + wv) * 512]);
    __syncthreads();
#pragma unroll
    for (int ky = 0; ky < 3; ++ky) {
      const int rb = (wv + ky) * 2112;
#pragma unroll
      for (int kx = 0; kx < 3; ++kx) {
        const int pos = ky * 3 + kx;
#pragma unroll
        for (int ks = 0; ks < 2; ++ks) {
          short8 Bf[NT];
#pragma unroll
          for (int nt = 0; nt < NT; ++nt)
            Bf[nt] = *(const short8*)&s_w[((pos * 2 + ks) * NT + nt) * 512 + lane * 8];
          const int sb = ks * 2 + lh;
#pragma unroll
          for (int Mt = 0; Mt < 2; ++Mt) {
            const int col = Mt * 32 + kx + lc;
            short8 Af =
                *(const short8*)&s_in[rb + (col << 5) + ((sb ^ ((col >> 1) & 3)) << 3)];
#pragma unroll
            for (int nt = 0; nt < NT; ++nt)
              acc[Mt][nt] =
                  __builtin_amdgcn_mfma_f32_32x32x16_bf16(Af, Bf[nt], acc[Mt][nt], 0, 0, 0);
          }
        }
      }
    }
  }

  // ---- epilogue ----
  const int y = y0 + wv;
  const bool yok = (y < H);
  if (HEAD) {
    if (yok) {
#pragma unroll
      for (int Mt = 0; Mt < 2; ++Mt)
#pragma unroll
        for (int r = 0; r < 16; ++r) {
          int m = (r & 3) + 8 * (r >> 2) + 4 * lh;
          int x = x0 + Mt * 32 + m;
          if (x < W) {
            size_t sp = (size_t)y * W + x;
            float v = acc[Mt][0][r];
            if (lc < 21) atomicAdd(&oba[(size_t)lc * (size_t)(H * W) + sp], v);
            else if (lc < 24) atomicAdd(&obb[(size_t)(lc - 21) * (size_t)(H * W) + sp], v);
          }
        }
    }
    return;
  }

  const int Ntot = Ntg * 32;
  if (yok) {
#pragma unroll
    for (int Mt = 0; Mt < 2; ++Mt)
#pragma unroll
      for (int r = 0; r < 16; ++r) {
        int m = (r & 3) + 8 * (r >> 2) + 4 * lh;
        int x = x0 + Mt * 32 + m;
        if (x < W) {
          size_t sp = (size_t)y * W + x;
#pragma unroll
          for (int nt = 0; nt < NT; ++nt) {
            int oc = (z * NT + nt) * 32 + lc;
            obf[sp * Ntot + oc] = f2bf(acc[Mt][nt][r]);
          }
        }
      }
  }

  if (STATS) {
    float s1[NT], s2[NT];
#pragma unroll
    for (int nt = 0; nt < NT; ++nt) { s1[nt] = 0.f; s2[nt] = 0.f; }
    if (yok) {
#pragma unroll
      for (int Mt = 0; Mt < 2; ++Mt)
#pragma unroll
        for (int r = 0; r < 16; ++r) {
          int m = (r & 3) + 8 * (r >> 2) + 4 * lh;
          int x = x0 + Mt * 32 + m;
          if (x < W) {
#pragma unroll
            for (int nt = 0; nt < NT; ++nt) {
              float v = acc[Mt][nt][r];
              s1[nt] += v;
              s2[nt] += v * v;
            }
          }
        }
    }
#pragma unroll
    for (int nt = 0; nt < NT; ++nt) {
      s1[nt] += __shfl_xor(s1[nt], 32);
      s2[nt] += __shfl_xor(s2[nt], 32);
    }
    __syncthreads();  // all MFMA LDS reads done; reuse s_in as fp32 scratch
    float* red = (float*)s_in;
    if (lh == 0) {
#pragma unroll
      for (int nt = 0; nt < NT; ++nt) {
        red[(wv * NT + nt) * 32 + lc] = s1[nt];
        red[8 * NT * 32 + (wv * NT + nt) * 32 + lc] = s2[nt];
      }
    }
    __syncthreads();
    if (wv == 0 && lh == 0) {
#pragma unroll
      for (int nt = 0; nt < NT; ++nt) {
        float a = 0.f, b = 0.f;
#pragma unroll
        for (int w8 = 0; w8 < 8; ++w8) {
          a += red[(w8 * NT + nt) * 32 + lc];
          b += red[8 * NT * 32 + (w8 * NT + nt) * 32 + lc];
        }
        int ch = (z * NT + nt) * 32 + lc;
        atomicAdd(&statacc[ch], a);
        atomicAdd(&statacc[ch + 256], b);
      }
    }
  }
}

// ------------------------------------------------------------------
// BN finalize + vectorized elementwise (4 channels / thread)
// ------------------------------------------------------------------

__global__ void bn_finalize(const float* __restrict__ acc, const float* __restrict__ g,
                            const float* __restrict__ b, float* __restrict__ ss, int C,
                            float invN) {
  int c = threadIdx.x;
  if (c >= C) return;
  float m = acc[c] * invN;
  float v = acc[c + 256] * invN - m * m;
  v = fmaxf(v, 0.f);
  float inv = rsqrtf(v + BN_EPS);
  float sc = g[c] * inv;
  ss[c] = sc;
  ss[c + 256] = b[c] - m * sc;
}

__device__ __forceinline__ float bnrl(ushort_t u, float sc, float sh) {
  return fmaxf(bf2f(u) * sc + sh, 0.f);
}

// BN+relu+2x2pool from bf16 HWC (natural) into padded SWIZZLED bf16 HWC
__global__ __launch_bounds__(256) void bn_relu_pool_pad4(
    const ushort_t* __restrict__ in, const float* __restrict__ ss,
    ushort_t* __restrict__ out, int Wi, int OW, int OH, int C, int cshift2, int PWo) {
  int idx = blockIdx.x * 256 + threadIdx.x;
  int total = OH * OW * (C >> 2);
  if (idx >= total) return;
  int cq = idx & ((C >> 2) - 1);
  int p = idx >> cshift2;
  int ox = p % OW;
  int oy = p / OW;
  int c = cq << 2;
  float4 scv = *(const float4*)&ss[c];
  float4 shv = *(const float4*)&ss[c + 256];
  const ushort_t* ip = in + ((size_t)(2 * oy) * Wi + 2 * ox) * C + c;
  ushort4 a0 = *(const ushort4*)(ip);
  ushort4 a1 = *(const ushort4*)(ip + C);
  ushort4 a2 = *(const ushort4*)(ip + (size_t)Wi * C);
  ushort4 a3 = *(const ushort4*)(ip + (size_t)Wi * C + C);
  ushort4 o;
  o.x = f2bf(fmaxf(fmaxf(bnrl(a0.x, scv.x, shv.x), bnrl(a1.x, scv.x, shv.x)),
                   fmaxf(bnrl(a2.x, scv.x, shv.x), bnrl(a3.x, scv.x, shv.x))));
  o.y = f2bf(fmaxf(fmaxf(bnrl(a0.y, scv.y, shv.y), bnrl(a1.y, scv.y, shv.y)),
                   fmaxf(bnrl(a2.y, scv.y, shv.y), bnrl(a3.y, scv.y, shv.y))));
  o.z = f2bf(fmaxf(fmaxf(bnrl(a0.z, scv.z, shv.z), bnrl(a1.z, scv.z, shv.z)),
                   fmaxf(bnrl(a2.z, scv.z, shv.z), bnrl(a3.z, scv.z, shv.z))));
  o.w = f2bf(fmaxf(fmaxf(bnrl(a0.w, scv.w, shv.w), bnrl(a1.w, scv.w, shv.w)),
                   fmaxf(bnrl(a2.w, scv.w, shv.w), bnrl(a3.w, scv.w, shv.w))));
  int xp = ox + 1;
  *(ushort4*)&out[((size_t)(oy + 1) * PWo + xp) * C + swz_c(c, xp)] = o;
}

// BN+relu (no pool) from bf16 HWC into padded SWIZZLED bf16 HWC
__global__ __launch_bounds__(256) void bn_relu_pad4(const ushort_t* __restrict__ in,
                                                    const float* __restrict__ ss,
                                                    ushort_t* __restrict__ out, int Wi,
                                                    int C, int cshift2, int PWo) {
  int idx = blockIdx.x * 256 + threadIdx.x;
  int total = Wi * Wi * (C >> 2);
  if (idx >= total) return;
  int cq = idx & ((C >> 2) - 1);
  int p = idx >> cshift2;
  int x = p % Wi;
  int y = p / Wi;
  int c = cq << 2;
  float4 scv = *(const float4*)&ss[c];
  float4 shv = *(const float4*)&ss[c + 256];
  ushort4 a = *(const ushort4*)&in[(size_t)p * C + c];
  ushort4 o;
  o.x = f2bf(bnrl(a.x, scv.x, shv.x));
  o.y = f2bf(bnrl(a.y, scv.y, shv.y));
  o.z = f2bf(bnrl(a.z, scv.z, shv.z));
  o.w = f2bf(bnrl(a.w, scv.w, shv.w));
  int xp = x + 1;
  *(ushort4*)&out[((size_t)(y + 1) * PWo + xp) * C + swz_c(c, xp)] = o;
}

// ------------------------------------------------------------------

extern "C" void kernel_launch(void* const* d_in, const int* in_sizes, int n_in,
                              void* d_out, int out_size, void* d_ws, size_t ws_size,
                              hipStream_t stream) {
  (void)in_sizes; (void)n_in; (void)out_size; (void)ws_size;
  const float* pillars = (const float*)d_in[0];
  const int* coords = (const int*)d_in[1];
  const float* lin_w = (const float*)d_in[2];
  const float* lin_b = (const float*)d_in[3];
  const float* pfn_g = (const float*)d_in[4];
  const float* pfn_b = (const float*)d_in[5];
  const float* c1_w = (const float*)d_in[6];
  const float* c1_b = (const float*)d_in[7];
  const float* bn1_g = (const float*)d_in[8];
  const float* bn1_b = (const float*)d_in[9];
  const float* c2_w = (const float*)d_in[10];
  const float* c2_b = (const float*)d_in[11];
  const float* bn2_g = (const float*)d_in[12];
  const float* bn2_b = (const float*)d_in[13];
  const float* h1_w = (const float*)d_in[14];
  const float* h1_b = (const float*)d_in[15];
  const float* hbn_g = (const float*)d_in[16];
  const float* hbn_b = (const float*)d_in[17];
  const float* hb_w = (const float*)d_in[18];
  const float* hb_b = (const float*)d_in[19];
  const float* hc_w = (const float*)d_in[20];
  const float* hc_b = (const float*)d_in[21];
  float* out = (float*)d_out;

  // ---- workspace layout (bytes) ----
  char* ws = (char*)d_ws;
  float* pfn_acc = (float*)(ws + 0);         // 512 B
  float* pfn_ss  = (float*)(ws + 512);       // 512 B
  float* bn_acc1 = (float*)(ws + 1024);      // 2048 B
  float* bn_acc2 = (float*)(ws + 3072);      // 2048 B
  float* bn_acc3 = (float*)(ws + 5120);      // 2048 B
  float* ss1     = (float*)(ws + 7168);      // 2048 B
  float* ss2     = (float*)(ws + 9216);      // 2048 B
  float* ss3     = (float*)(ws + 11264);     // 2048 B
  int* winner    = (int*)(ws + 13312);       // 1774224 B
  float* feats   = (float*)(ws + 1787648);   // 5120000 B
  ushort_t* canvas = (ushort_t*)(ws + 6907648);     // 706x680x64  = 61450240 B
  ushort_t* c1out  = (ushort_t*)(ws + 68357888);    // 666x666x64  = 56775168 B
  ushort_t* c2in   = (ushort_t*)(ws + 125133056);   // 386x338x64  = 16699904 B
  ushort_t* c2out  = (ushort_t*)(ws + 141832960);   // 333x333x128 = 28387584 B
  ushort_t* h1in   = (ushort_t*)(ws + 170220544);   // 194x170x128 = 8442880 B
  ushort_t* h1out  = (ushort_t*)(ws + 178663424);   // 166x166x256 = 14108672 B
  ushort_t* hdin   = (ushort_t*)(ws + 192772096);   // 194x170x256 = 16885760 B
  ushort_t* w2c1   = (ushort_t*)(ws + 209657856);   // 73728 B
  ushort_t* w2c2   = (ushort_t*)(ws + 209731584);   // 147456 B
  ushort_t* w2h1   = (ushort_t*)(ws + 209879040);   // 589824 B
  ushort_t* w2hd   = (ushort_t*)(ws + 210468864);   // 147456 B

  const int HW3 = 166 * 166;

  // ---- upfront zero-init ----
  hipMemsetAsync(ws, 0, 7168, stream);  // pfn_acc/pfn_ss/bn_acc1-3
  hipMemsetAsync(winner, 0xFF, 1774224, stream);
  hipMemsetAsync(canvas, 0, 61450240, stream);
  hipMemsetAsync(c2in, 0, 16699904, stream);
  hipMemsetAsync(h1in, 0, 8442880, stream);
  hipMemsetAsync(hdin, 0, 16885760, stream);
  hipMemsetAsync(out, 0, (size_t)24 * HW3 * 4, stream);  // head accumulates via atomics

  // ---- weight prep ([cc32][pos][ks][ntg][lane][8]) ----
  prep_w<<<18, 256, 0, stream>>>(c1_w, w2c1, 64, 64, 2, 2);
  prep_w<<<36, 256, 0, stream>>>(c2_w, w2c2, 64, 128, 4, 2);
  prep_w<<<144, 256, 0, stream>>>(h1_w, w2h1, 128, 256, 8, 4);
  prep_w_head<<<36, 256, 0, stream>>>(hb_w, hc_w, w2hd);

  // ---- PFN ----
  pfn_stats<<<625, 256, 0, stream>>>(pillars, lin_w, lin_b, pfn_acc);
  pfn_finalize<<<1, 64, 0, stream>>>(pfn_acc, pfn_g, pfn_b, pfn_ss);
  pfn_feats<<<5000, 256, 0, stream>>>(pillars, lin_w, lin_b, pfn_ss, feats);

  // ---- scatter ----
  scatter_winner<<<(20000 + 255) / 256, 256, 0, stream>>>(coords, winner, 20000);
  scatter_img<<<5000, 256, 0, stream>>>(coords, winner, feats, canvas, 20000, 706);

  // ---- conv1: 666x666, 64->64, 2 K-chunks (stats fused) ----
  conv_mfma<2, false, true><<<dim3(11, 84, 1), 512, 0, stream>>>(
      canvas, w2c1, c1_b, nullptr, c1out, nullptr, nullptr, bn_acc1, 706, 666, 666, 64,
      2, 2);
  bn_finalize<<<1, 256, 0, stream>>>(bn_acc1, bn1_g, bn1_b, ss1, 64, 1.f / 443556.f);
  bn_relu_pool_pad4<<<(333 * 333 * 16 + 255) / 256, 256, 0, stream>>>(
      c1out, ss1, c2in, 666, 333, 333, 64, 4, 386);

  // ---- conv2: 333x333, 64->128, 2 K-chunks (stats fused) ----
  conv_mfma<2, false, true><<<dim3(6, 42, 2), 512, 0, stream>>>(
      c2in, w2c2, c2_b, nullptr, c2out, nullptr, nullptr, bn_acc2, 386, 333, 333, 64, 2,
      4);
  bn_finalize<<<1, 256, 0, stream>>>(bn_acc2, bn2_g, bn2_b, ss2, 128, 1.f / 110889.f);
  bn_relu_pool_pad4<<<(166 * 166 * 32 + 255) / 256, 256, 0, stream>>>(
      c2out, ss2, h1in, 333, 166, 166, 128, 5, 194);

  // ---- h1: 166x166, 128->256, NT=1 z=8, 4 K-chunks (stats fused) ----
  conv_mfma<1, false, true><<<dim3(3, 21, 8), 512, 0, stream>>>(
      h1in, w2h1, h1_b, nullptr, h1out, nullptr, nullptr, bn_acc3, 194, 166, 166, 128, 4,
      8);
  bn_finalize<<<1, 256, 0, stream>>>(bn_acc3, hbn_g, hbn_b, ss3, 256, 1.f / 27556.f);
  bn_relu_pad4<<<(HW3 * 64 + 255) / 256, 256, 0, stream>>>(h1out, ss3, hdin, 166, 256, 6,
                                                           194);

  // ---- heads: 166x166, 256->(21+3), K-split z=8, fp32 atomics into d_out ----
  conv_mfma<1, true, false><<<dim3(3, 21, 8), 512, 0, stream>>>(
      hdin, w2hd, hb_b, hc_b, nullptr, out, out + (size_t)21 * HW3, nullptr, 194, 166,
      166, 256, 1, 1);
}

// Round 6
// 493.736 us; speedup vs baseline: 1.1234x; 1.1234x over previous
//
#include <hip/hip_runtime.h>
#include <hip/hip_bf16.h>
#include <cstdint>
#include <cstddef>

#define BN_EPS 1e-5f

typedef short short8 __attribute__((ext_vector_type(8)));
typedef float float16 __attribute__((ext_vector_type(16)));
typedef unsigned short ushort_t;

__device__ __forceinline__ float bf2f(ushort_t u) {
  return __uint_as_float(((unsigned int)u) << 16);
}
__device__ __forceinline__ ushort_t f2bf(float f) {
  unsigned int u = __float_as_uint(f);
  u += 0x7FFFu + ((u >> 16) & 1u);
  return (ushort_t)(u >> 16);
}

// ------------------------------------------------------------------
// PFN (fp32)
// ------------------------------------------------------------------

__global__ __launch_bounds__(256) void pfn_stats(
    const float* __restrict__ pillars, const float* __restrict__ lin_w,
    const float* __restrict__ lin_b, float* __restrict__ acc) {
  __shared__ float s_p[288];
  __shared__ float red[512];
  int tid = threadIdx.x;
  int c = tid & 63, rs = tid >> 6;
  float w[9];
#pragma unroll
  for (int d = 0; d < 9; ++d) w[d] = lin_w[c * 9 + d];
  float bl = lin_b[c];
  float s = 0.f, s2 = 0.f;
  long base_row = (long)blockIdx.x * 1024;
  for (int ch = 0; ch < 32; ++ch) {
    long crow = base_row + ch * 32;
    __syncthreads();
    for (int i = tid; i < 288; i += 256) s_p[i] = pillars[crow * 9 + i];
    __syncthreads();
#pragma unroll
    for (int k = 0; k < 8; ++k) {
      const float* pr = &s_p[(rs * 8 + k) * 9];
      float y = bl;
#pragma unroll
      for (int d = 0; d < 9; ++d) y += pr[d] * w[d];
      s += y;
      s2 += y * y;
    }
  }
  red[tid] = s;
  red[tid + 256] = s2;
  __syncthreads();
  if (rs == 0) {
    float ts = red[c] + red[c + 64] + red[c + 128] + red[c + 192];
    float t2 = red[256 + c] + red[256 + c + 64] + red[256 + c + 128] + red[256 + c + 192];
    atomicAdd(&acc[c], ts);
    atomicAdd(&acc[c + 64], t2);
  }
}

__global__ void pfn_finalize(const float* __restrict__ acc, const float* __restrict__ g,
                             const float* __restrict__ b, float* __restrict__ ss) {
  int c = threadIdx.x;  // 64 threads
  const float invN = 1.f / 640000.f;
  float m = acc[c] * invN;
  float v = acc[c + 64] * invN - m * m;
  v = fmaxf(v, 0.f);
  float inv = rsqrtf(v + BN_EPS);
  float sc = g[c] * inv;
  ss[c] = sc;
  ss[c + 64] = b[c] - m * sc;
}

__global__ __launch_bounds__(256) void pfn_feats(
    const float* __restrict__ pillars, const float* __restrict__ lin_w,
    const float* __restrict__ lin_b, const float* __restrict__ ss,
    float* __restrict__ feats) {
  __shared__ float s_p[1152];
  int tid = threadIdx.x;
  int c = tid & 63, pe = tid >> 6;
  long pb = (long)blockIdx.x * 4;
  for (int i = tid; i < 1152; i += 256) s_p[i] = pillars[pb * 288 + i];
  float w[9];
#pragma unroll
  for (int d = 0; d < 9; ++d) w[d] = lin_w[c * 9 + d];
  float bl = lin_b[c];
  float sc = ss[c], sh = ss[c + 64];
  __syncthreads();
  const float* pp = &s_p[pe * 288];
  float m = -1e30f;
#pragma unroll 4
  for (int n = 0; n < 32; ++n) {
    float y = bl;
#pragma unroll
    for (int d = 0; d < 9; ++d) y += pp[n * 9 + d] * w[d];
    float v = fmaxf(y * sc + sh, 0.f);
    m = fmaxf(m, v);
  }
  feats[(pb + pe) * 64 + c] = m;
}

// ------------------------------------------------------------------
// Scatter into padded bf16 HWC canvas (numpy last-write-wins)
// ------------------------------------------------------------------

__global__ void scatter_winner(const int* __restrict__ coords, int* __restrict__ winner,
                               int P) {
  int p = blockIdx.x * 256 + threadIdx.x;
  if (p >= P) return;
  int y = coords[p * 3 + 1], x = coords[p * 3 + 2];
  if (y >= 0 && y < 666 && x >= 0 && x < 666) atomicMax(&winner[y * 666 + x], p);
}

__global__ void scatter_img(const int* __restrict__ coords, const int* __restrict__ winner,
                            const float* __restrict__ feats, ushort_t* __restrict__ img,
                            int P, int PW) {
  int idx = blockIdx.x * 256 + threadIdx.x;
  int p = idx >> 6, c = idx & 63;
  if (p >= P) return;
  int y = coords[p * 3 + 1], x = coords[p * 3 + 2];
  if (y >= 0 && y < 666 && x >= 0 && x < 666) {
    if (winner[y * 666 + x] == p)
      img[((size_t)(y + 1) * PW + (x + 1)) * 64 + c] = f2bf(feats[p * 64 + c]);
  }
}

// ------------------------------------------------------------------
// Weight prep: OIHW fp32 -> fragment-ordered bf16 (R2 layout, Kc=32)
// layout: [cc32][pos][s(2)][ntg][lane 64][8]
//   lane l: n = ntg*32 + (l&31); c = cc*32 + s*16 + (l>>5)*8 + j
// ------------------------------------------------------------------

__global__ void prep_w(const float* __restrict__ w, ushort_t* __restrict__ w2, int C,
                       int N, int Ntg, int chunks) {
  int u = blockIdx.x * 256 + threadIdx.x;
  int total = chunks * 9 * 2 * Ntg * 64;
  if (u >= total) return;
  int l = u & 63;
  int g = u >> 6;
  int ntg = g % Ntg;
  int g2 = g / Ntg;
  int s = g2 & 1;
  int g3 = g2 >> 1;
  int pos = g3 % 9;
  int cc = g3 / 9;
  int n = ntg * 32 + (l & 31);
  int c0 = cc * 32 + s * 16 + (l >> 5) * 8;
  ushort_t o8[8];
#pragma unroll
  for (int j = 0; j < 8; ++j) {
    int c = c0 + j;
    float v = (n < N && c < C) ? w[((size_t)n * C + c) * 9 + pos] : 0.f;
    o8[j] = f2bf(v);
  }
  *(uint4*)&w2[(size_t)u * 8] = *(const uint4*)o8;
}

// merged heads: n<21 -> hb_w, 21..23 -> hc_w, >=24 -> 0.  C=256, Ntg=1, chunks=8
__global__ void prep_w_head(const float* __restrict__ hb, const float* __restrict__ hc,
                            ushort_t* __restrict__ w2) {
  int u = blockIdx.x * 256 + threadIdx.x;
  int total = 8 * 9 * 2 * 64;
  if (u >= total) return;
  int l = u & 63;
  int g = u >> 6;
  int s = g & 1;
  int g3 = g >> 1;
  int pos = g3 % 9;
  int cc = g3 / 9;
  int n = l & 31;
  int c0 = cc * 32 + s * 16 + (l >> 5) * 8;
  ushort_t o8[8];
#pragma unroll
  for (int j = 0; j < 8; ++j) {
    int c = c0 + j;
    float v = 0.f;
    if (n < 21) v = hb[((size_t)n * 256 + c) * 9 + pos];
    else if (n < 24) v = hc[((size_t)(n - 21) * 256 + c) * 9 + pos];
    o8[j] = f2bf(v);
  }
  *(uint4*)&w2[(size_t)u * 8] = *(const uint4*)o8;
}

// ------------------------------------------------------------------
// Implicit-GEMM 3x3 conv via v_mfma_f32_32x32x16_bf16 — R2 structure.
// Block = 4 waves. Tile 64 px x 4 rows, NT*32 oc per block.
// K chunked by 32 ch; per chunk stage input 6x66x32 (xor-swizzled) + weights.
// LDS 62208 B -> 2 blocks/CU.  HEAD: blockIdx.z = K-split, atomic epilogue.
// STATS: fused per-channel sum/sumsq block-reduce + atomicAdd.
// ------------------------------------------------------------------

template <int NT, bool HEAD, bool STATS>
__global__ __launch_bounds__(256, 2) void conv_mfma(
    const ushort_t* __restrict__ in, const ushort_t* __restrict__ w2,
    const float* __restrict__ bias, const float* __restrict__ bias2,
    ushort_t* __restrict__ obf, float* __restrict__ oba, float* __restrict__ obb,
    float* __restrict__ statacc, int PW, int W, int H, int C, int nchunks, int Ntg) {
  __shared__ ushort_t s_in[6 * 66 * 32];            // 25344 B
  __shared__ ushort_t s_w[9 * 2 * NT * 512];        // 18432*NT B
  const int tid = threadIdx.x;
  const int lane = tid & 63, wv = tid >> 6;
  const int lc = lane & 31, lh = lane >> 5;
  const int x0 = blockIdx.x * 64, y0 = blockIdx.y * 4;
  const int z = blockIdx.z;
  const int cc0 = HEAD ? z * nchunks : 0;
  const int z_oc = HEAD ? 0 : z;

  // per-lane A-address precompute
  int pc[2][2][3];
#pragma unroll
  for (int s = 0; s < 2; ++s)
#pragma unroll
    for (int Mt = 0; Mt < 2; ++Mt)
#pragma unroll
      for (int kx = 0; kx < 3; ++kx) {
        int col = Mt * 32 + kx + lc;
        int q = (2 * s + lh) ^ ((col >> 1) & 3);
        pc[s][Mt][kx] = col * 32 + q * 8;
      }

  float bv[NT];
#pragma unroll
  for (int nt = 0; nt < NT; ++nt) {
    if (HEAD) {
      bv[nt] = (z == 0) ? (lc < 21 ? bias[lc] : (lc < 24 ? bias2[lc - 21] : 0.f)) : 0.f;
    } else {
      bv[nt] = bias[(z * NT + nt) * 32 + lc];
    }
  }
  float16 acc[2][NT];
#pragma unroll
  for (int Mt = 0; Mt < 2; ++Mt)
#pragma unroll
    for (int nt = 0; nt < NT; ++nt)
#pragma unroll
      for (int r = 0; r < 16; ++r) acc[Mt][nt][r] = bv[nt];

  const ushort_t* inbase = in + ((size_t)y0 * PW + x0) * C;
  for (int cc = 0; cc < nchunks; ++cc) {
    const int ccg = cc0 + cc;
    __syncthreads();
    // stage input chunk: 6 rows x 66 cols x 4 groups of 8ch (16 B units)
    for (int u = tid; u < 1584; u += 256) {
      int r = u / 264;
      int sr = u - r * 264;
      int col = sr >> 2, f = sr & 3;
      int g = f ^ ((col >> 1) & 3);
      const ushort_t* src = inbase + ((size_t)r * PW + col) * C + ccg * 32 + g * 8;
      *(uint4*)&s_in[(r * 66 + col) * 32 + f * 8] = *(const uint4*)src;
    }
    // stage weight slice: [pos*2+s][nt] x 64 lanes x 16 B
    const int NW = NT * 1152;
    for (int u = tid; u < NW; u += 256) {
      int l16 = u & 63, grp = u >> 6;
      int nt = grp % NT, ps = grp / NT;
      const ushort_t* src =
          w2 + ((size_t)((ccg * 18 + ps) * Ntg + z_oc * NT + nt) * 64 + l16) * 8;
      *(uint4*)&s_w[(size_t)u * 8] = *(const uint4*)src;
    }
    __syncthreads();
#pragma unroll
    for (int ky = 0; ky < 3; ++ky) {
      int rowoff = (wv + ky) * (66 * 32);
#pragma unroll
      for (int kx = 0; kx < 3; ++kx) {
        const int pos = ky * 3 + kx;
#pragma unroll
        for (int s = 0; s < 2; ++s) {
          short8 Bf[NT];
#pragma unroll
          for (int nt = 0; nt < NT; ++nt)
            Bf[nt] = *(const short8*)&s_w[((pos * 2 + s) * NT + nt) * 512 + lane * 8];
#pragma unroll
          for (int Mt = 0; Mt < 2; ++Mt) {
            short8 Af = *(const short8*)&s_in[rowoff + pc[s][Mt][kx]];
#pragma unroll
            for (int nt = 0; nt < NT; ++nt)
              acc[Mt][nt] =
                  __builtin_amdgcn_mfma_f32_32x32x16_bf16(Af, Bf[nt], acc[Mt][nt], 0, 0, 0);
          }
        }
      }
    }
  }

  // ---- epilogue ----
  const int y = y0 + wv;
  const bool yok = (y < H);
  if (HEAD) {
    if (yok) {
#pragma unroll
      for (int Mt = 0; Mt < 2; ++Mt)
#pragma unroll
        for (int r = 0; r < 16; ++r) {
          int m = (r & 3) + 8 * (r >> 2) + 4 * lh;
          int x = x0 + Mt * 32 + m;
          if (x < W) {
            size_t sp = (size_t)y * W + x;
            float v = acc[Mt][0][r];
            if (lc < 21) atomicAdd(&oba[(size_t)lc * (size_t)(H * W) + sp], v);
            else if (lc < 24) atomicAdd(&obb[(size_t)(lc - 21) * (size_t)(H * W) + sp], v);
          }
        }
    }
    return;
  }

  const int Ntot = Ntg * 32;
  if (yok) {
#pragma unroll
    for (int Mt = 0; Mt < 2; ++Mt)
#pragma unroll
      for (int r = 0; r < 16; ++r) {
        int m = (r & 3) + 8 * (r >> 2) + 4 * lh;
        int x = x0 + Mt * 32 + m;
        if (x < W) {
          size_t sp = (size_t)y * W + x;
#pragma unroll
          for (int nt = 0; nt < NT; ++nt) {
            int oc = (z * NT + nt) * 32 + lc;
            obf[sp * Ntot + oc] = f2bf(acc[Mt][nt][r]);
          }
        }
      }
  }

  if (STATS) {
    float s1[NT], s2[NT];
#pragma unroll
    for (int nt = 0; nt < NT; ++nt) { s1[nt] = 0.f; s2[nt] = 0.f; }
    if (yok) {
#pragma unroll
      for (int Mt = 0; Mt < 2; ++Mt)
#pragma unroll
        for (int r = 0; r < 16; ++r) {
          int m = (r & 3) + 8 * (r >> 2) + 4 * lh;
          int x = x0 + Mt * 32 + m;
          if (x < W) {
#pragma unroll
            for (int nt = 0; nt < NT; ++nt) {
              float v = acc[Mt][nt][r];
              s1[nt] += v;
              s2[nt] += v * v;
            }
          }
        }
    }
#pragma unroll
    for (int nt = 0; nt < NT; ++nt) {
      s1[nt] += __shfl_xor(s1[nt], 32);
      s2[nt] += __shfl_xor(s2[nt], 32);
    }
    __syncthreads();  // all MFMA LDS reads done; reuse s_in as fp32 scratch
    float* red = (float*)s_in;
    if (lh == 0) {
#pragma unroll
      for (int nt = 0; nt < NT; ++nt) {
        red[(wv * NT + nt) * 32 + lc] = s1[nt];
        red[4 * NT * 32 + (wv * NT + nt) * 32 + lc] = s2[nt];
      }
    }
    __syncthreads();
    if (wv == 0 && lh == 0) {
#pragma unroll
      for (int nt = 0; nt < NT; ++nt) {
        float a = 0.f, b = 0.f;
#pragma unroll
        for (int w4 = 0; w4 < 4; ++w4) {
          a += red[(w4 * NT + nt) * 32 + lc];
          b += red[4 * NT * 32 + (w4 * NT + nt) * 32 + lc];
        }
        int ch = (z * NT + nt) * 32 + lc;
        atomicAdd(&statacc[ch], a);
        atomicAdd(&statacc[ch + 256], b);
      }
    }
  }
}

// ------------------------------------------------------------------
// BN finalize + vectorized elementwise (4 channels / thread, natural order)
// ------------------------------------------------------------------

__global__ void bn_finalize(const float* __restrict__ acc, const float* __restrict__ g,
                            const float* __restrict__ b, float* __restrict__ ss, int C,
                            float invN) {
  int c = threadIdx.x;
  if (c >= C) return;
  float m = acc[c] * invN;
  float v = acc[c + 256] * invN - m * m;
  v = fmaxf(v, 0.f);
  float inv = rsqrtf(v + BN_EPS);
  float sc = g[c] * inv;
  ss[c] = sc;
  ss[c + 256] = b[c] - m * sc;
}

__device__ __forceinline__ float bnrl(ushort_t u, float sc, float sh) {
  return fmaxf(bf2f(u) * sc + sh, 0.f);
}

// BN+relu+2x2pool from bf16 HWC (Wi wide) into padded bf16 HWC (PWo pitch)
__global__ __launch_bounds__(256) void bn_relu_pool_pad4(
    const ushort_t* __restrict__ in, const float* __restrict__ ss,
    ushort_t* __restrict__ out, int Wi, int OW, int OH, int C, int cshift2, int PWo) {
  int idx = blockIdx.x * 256 + threadIdx.x;
  int total = OH * OW * (C >> 2);
  if (idx >= total) return;
  int cq = idx & ((C >> 2) - 1);
  int p = idx >> cshift2;
  int ox = p % OW;
  int oy = p / OW;
  int c = cq << 2;
  float4 scv = *(const float4*)&ss[c];
  float4 shv = *(const float4*)&ss[c + 256];
  const ushort_t* ip = in + ((size_t)(2 * oy) * Wi + 2 * ox) * C + c;
  ushort4 a0 = *(const ushort4*)(ip);
  ushort4 a1 = *(const ushort4*)(ip + C);
  ushort4 a2 = *(const ushort4*)(ip + (size_t)Wi * C);
  ushort4 a3 = *(const ushort4*)(ip + (size_t)Wi * C + C);
  ushort4 o;
  o.x = f2bf(fmaxf(fmaxf(bnrl(a0.x, scv.x, shv.x), bnrl(a1.x, scv.x, shv.x)),
                   fmaxf(bnrl(a2.x, scv.x, shv.x), bnrl(a3.x, scv.x, shv.x))));
  o.y = f2bf(fmaxf(fmaxf(bnrl(a0.y, scv.y, shv.y), bnrl(a1.y, scv.y, shv.y)),
                   fmaxf(bnrl(a2.y, scv.y, shv.y), bnrl(a3.y, scv.y, shv.y))));
  o.z = f2bf(fmaxf(fmaxf(bnrl(a0.z, scv.z, shv.z), bnrl(a1.z, scv.z, shv.z)),
                   fmaxf(bnrl(a2.z, scv.z, shv.z), bnrl(a3.z, scv.z, shv.z))));
  o.w = f2bf(fmaxf(fmaxf(bnrl(a0.w, scv.w, shv.w), bnrl(a1.w, scv.w, shv.w)),
                   fmaxf(bnrl(a2.w, scv.w, shv.w), bnrl(a3.w, scv.w, shv.w))));
  *(ushort4*)&out[((size_t)(oy + 1) * PWo + (ox + 1)) * C + c] = o;
}

// BN+relu (no pool) from bf16 HWC into padded bf16 HWC
__global__ __launch_bounds__(256) void bn_relu_pad4(const ushort_t* __restrict__ in,
                                                    const float* __restrict__ ss,
                                                    ushort_t* __restrict__ out, int Wi,
                                                    int C, int cshift2, int PWo) {
  int idx = blockIdx.x * 256 + threadIdx.x;
  int total = Wi * Wi * (C >> 2);
  if (idx >= total) return;
  int cq = idx & ((C >> 2) - 1);
  int p = idx >> cshift2;
  int x = p % Wi;
  int y = p / Wi;
  int c = cq << 2;
  float4 scv = *(const float4*)&ss[c];
  float4 shv = *(const float4*)&ss[c + 256];
  ushort4 a = *(const ushort4*)&in[(size_t)p * C + c];
  ushort4 o;
  o.x = f2bf(bnrl(a.x, scv.x, shv.x));
  o.y = f2bf(bnrl(a.y, scv.y, shv.y));
  o.z = f2bf(bnrl(a.z, scv.z, shv.z));
  o.w = f2bf(bnrl(a.w, scv.w, shv.w));
  *(ushort4*)&out[((size_t)(y + 1) * PWo + (x + 1)) * C + c] = o;
}

// ------------------------------------------------------------------

extern "C" void kernel_launch(void* const* d_in, const int* in_sizes, int n_in,
                              void* d_out, int out_size, void* d_ws, size_t ws_size,
                              hipStream_t stream) {
  (void)in_sizes; (void)n_in; (void)out_size; (void)ws_size;
  const float* pillars = (const float*)d_in[0];
  const int* coords = (const int*)d_in[1];
  const float* lin_w = (const float*)d_in[2];
  const float* lin_b = (const float*)d_in[3];
  const float* pfn_g = (const float*)d_in[4];
  const float* pfn_b = (const float*)d_in[5];
  const float* c1_w = (const float*)d_in[6];
  const float* c1_b = (const float*)d_in[7];
  const float* bn1_g = (const float*)d_in[8];
  const float* bn1_b = (const float*)d_in[9];
  const float* c2_w = (const float*)d_in[10];
  const float* c2_b = (const float*)d_in[11];
  const float* bn2_g = (const float*)d_in[12];
  const float* bn2_b = (const float*)d_in[13];
  const float* h1_w = (const float*)d_in[14];
  const float* h1_b = (const float*)d_in[15];
  const float* hbn_g = (const float*)d_in[16];
  const float* hbn_b = (const float*)d_in[17];
  const float* hb_w = (const float*)d_in[18];
  const float* hb_b = (const float*)d_in[19];
  const float* hc_w = (const float*)d_in[20];
  const float* hc_b = (const float*)d_in[21];
  float* out = (float*)d_out;

  // ---- workspace layout (bytes) ----
  char* ws = (char*)d_ws;
  float* pfn_acc = (float*)(ws + 0);         // 512 B
  float* pfn_ss  = (float*)(ws + 512);       // 512 B
  float* bn_acc1 = (float*)(ws + 1024);      // 2048 B
  float* bn_acc2 = (float*)(ws + 3072);      // 2048 B
  float* bn_acc3 = (float*)(ws + 5120);      // 2048 B
  float* ss1     = (float*)(ws + 7168);      // 2048 B
  float* ss2     = (float*)(ws + 9216);      // 2048 B
  float* ss3     = (float*)(ws + 11264);     // 2048 B
  int* winner    = (int*)(ws + 13312);       // 1774224 B
  float* feats   = (float*)(ws + 1787648);   // 5120000 B
  ushort_t* canvas = (ushort_t*)(ws + 6907648);     // 706x670x64   = 60546560 B
  ushort_t* c1out  = (ushort_t*)(ws + 67454208);    // 666x666x64   = 56775168 B
  ushort_t* c2in   = (ushort_t*)(ws + 124229376);   // 386x338x64   = 16699904 B
  ushort_t* c2out  = (ushort_t*)(ws + 140929280);   // 333x333x128  = 28387584 B
  ushort_t* h1in   = (ushort_t*)(ws + 169316864);   // 194x170x128  = 8442880 B
  ushort_t* h1out  = (ushort_t*)(ws + 177759744);   // 166x166x256  = 14108672 B
  ushort_t* hdin   = (ushort_t*)(ws + 191868416);   // 194x170x256  = 16885760 B
  ushort_t* w2c1   = (ushort_t*)(ws + 208754176);   // 73728 B
  ushort_t* w2c2   = (ushort_t*)(ws + 208827904);   // 147456 B
  ushort_t* w2h1   = (ushort_t*)(ws + 208975360);   // 589824 B
  ushort_t* w2hd   = (ushort_t*)(ws + 209565184);   // 147456 B

  const int HW3 = 166 * 166;

  // ---- upfront zero-init ----
  hipMemsetAsync(ws, 0, 7168, stream);  // pfn_acc/pfn_ss/bn_acc1-3
  hipMemsetAsync(winner, 0xFF, 1774224, stream);
  hipMemsetAsync(canvas, 0, 60546560, stream);
  hipMemsetAsync(c2in, 0, 16699904, stream);
  hipMemsetAsync(h1in, 0, 8442880, stream);
  hipMemsetAsync(hdin, 0, 16885760, stream);
  hipMemsetAsync(out, 0, (size_t)24 * HW3 * 4, stream);  // head accumulates via atomics

  // ---- weight prep (Kc=32 layout) ----
  prep_w<<<18, 256, 0, stream>>>(c1_w, w2c1, 64, 64, 2, 2);
  prep_w<<<36, 256, 0, stream>>>(c2_w, w2c2, 64, 128, 4, 2);
  prep_w<<<144, 256, 0, stream>>>(h1_w, w2h1, 128, 256, 8, 4);
  prep_w_head<<<36, 256, 0, stream>>>(hb_w, hc_w, w2hd);

  // ---- PFN ----
  pfn_stats<<<625, 256, 0, stream>>>(pillars, lin_w, lin_b, pfn_acc);
  pfn_finalize<<<1, 64, 0, stream>>>(pfn_acc, pfn_g, pfn_b, pfn_ss);
  pfn_feats<<<5000, 256, 0, stream>>>(pillars, lin_w, lin_b, pfn_ss, feats);

  // ---- scatter ----
  scatter_winner<<<(20000 + 255) / 256, 256, 0, stream>>>(coords, winner, 20000);
  scatter_img<<<5000, 256, 0, stream>>>(coords, winner, feats, canvas, 20000, 706);

  // ---- conv1: 666x666, 64->64, 2 K-chunks (stats fused) ----
  conv_mfma<2, false, true><<<dim3(11, 167, 1), 256, 0, stream>>>(
      canvas, w2c1, c1_b, nullptr, c1out, nullptr, nullptr, bn_acc1, 706, 666, 666, 64,
      2, 2);
  bn_finalize<<<1, 256, 0, stream>>>(bn_acc1, bn1_g, bn1_b, ss1, 64, 1.f / 443556.f);
  bn_relu_pool_pad4<<<(333 * 333 * 16 + 255) / 256, 256, 0, stream>>>(
      c1out, ss1, c2in, 666, 333, 333, 64, 4, 386);

  // ---- conv2: 333x333, 64->128, 2 K-chunks (stats fused) ----
  conv_mfma<2, false, true><<<dim3(6, 84, 2), 256, 0, stream>>>(
      c2in, w2c2, c2_b, nullptr, c2out, nullptr, nullptr, bn_acc2, 386, 333, 333, 64, 2,
      4);
  bn_finalize<<<1, 256, 0, stream>>>(bn_acc2, bn2_g, bn2_b, ss2, 128, 1.f / 110889.f);
  bn_relu_pool_pad4<<<(166 * 166 * 32 + 255) / 256, 256, 0, stream>>>(
      c2out, ss2, h1in, 333, 166, 166, 128, 5, 194);

  // ---- h1: 166x166, 128->256, 4 K-chunks (stats fused) ----
  conv_mfma<2, false, true><<<dim3(3, 42, 4), 256, 0, stream>>>(
      h1in, w2h1, h1_b, nullptr, h1out, nullptr, nullptr, bn_acc3, 194, 166, 166, 128, 4,
      8);
  bn_finalize<<<1, 256, 0, stream>>>(bn_acc3, hbn_g, hbn_b, ss3, 256, 1.f / 27556.f);
  bn_relu_pad4<<<(HW3 * 64 + 255) / 256, 256, 0, stream>>>(h1out, ss3, hdin, 166, 256, 6,
                                                           194);

  // ---- heads: 166x166, 256->(21+3), K-split z=2 (4 chunks each), atomics ----
  conv_mfma<1, true, false><<<dim3(3, 42, 2), 256, 0, stream>>>(
      hdin, w2hd, hb_b, hc_b, nullptr, out, out + (size_t)21 * HW3, nullptr, 194, 166,
      166, 256, 4, 1);
}

// Round 7
// 435.315 us; speedup vs baseline: 1.2741x; 1.1342x over previous
//
#include <hip/hip_runtime.h>
#include <hip/hip_bf16.h>
#include <cstdint>
#include <cstddef>

#define BN_EPS 1e-5f

typedef short short8 __attribute__((ext_vector_type(8)));
typedef float float16 __attribute__((ext_vector_type(16)));
typedef unsigned short ushort_t;

__device__ __forceinline__ float bf2f(ushort_t u) {
  return __uint_as_float(((unsigned int)u) << 16);
}
__device__ __forceinline__ ushort_t f2bf(float f) {
  unsigned int u = __float_as_uint(f);
  u += 0x7FFFu + ((u >> 16) & 1u);
  return (ushort_t)(u >> 16);
}

// ------------------------------------------------------------------
// PFN (fp32)
// ------------------------------------------------------------------

__global__ __launch_bounds__(256) void pfn_stats(
    const float* __restrict__ pillars, const float* __restrict__ lin_w,
    const float* __restrict__ lin_b, float* __restrict__ acc) {
  __shared__ float s_p[288];
  __shared__ float red[512];
  int tid = threadIdx.x;
  int c = tid & 63, rs = tid >> 6;
  float w[9];
#pragma unroll
  for (int d = 0; d < 9; ++d) w[d] = lin_w[c * 9 + d];
  float bl = lin_b[c];
  float s = 0.f, s2 = 0.f;
  long base_row = (long)blockIdx.x * 1024;
  for (int ch = 0; ch < 32; ++ch) {
    long crow = base_row + ch * 32;
    __syncthreads();
    for (int i = tid; i < 288; i += 256) s_p[i] = pillars[crow * 9 + i];
    __syncthreads();
#pragma unroll
    for (int k = 0; k < 8; ++k) {
      const float* pr = &s_p[(rs * 8 + k) * 9];
      float y = bl;
#pragma unroll
      for (int d = 0; d < 9; ++d) y += pr[d] * w[d];
      s += y;
      s2 += y * y;
    }
  }
  red[tid] = s;
  red[tid + 256] = s2;
  __syncthreads();
  if (rs == 0) {
    float ts = red[c] + red[c + 64] + red[c + 128] + red[c + 192];
    float t2 = red[256 + c] + red[256 + c + 64] + red[256 + c + 128] + red[256 + c + 192];
    atomicAdd(&acc[c], ts);
    atomicAdd(&acc[c + 64], t2);
  }
}

__global__ void pfn_finalize(const float* __restrict__ acc, const float* __restrict__ g,
                             const float* __restrict__ b, float* __restrict__ ss) {
  int c = threadIdx.x;  // 64 threads
  const float invN = 1.f / 640000.f;
  float m = acc[c] * invN;
  float v = acc[c + 64] * invN - m * m;
  v = fmaxf(v, 0.f);
  float inv = rsqrtf(v + BN_EPS);
  float sc = g[c] * inv;
  ss[c] = sc;
  ss[c + 64] = b[c] - m * sc;
}

__global__ __launch_bounds__(256) void pfn_feats(
    const float* __restrict__ pillars, const float* __restrict__ lin_w,
    const float* __restrict__ lin_b, const float* __restrict__ ss,
    float* __restrict__ feats) {
  __shared__ float s_p[1152];
  int tid = threadIdx.x;
  int c = tid & 63, pe = tid >> 6;
  long pb = (long)blockIdx.x * 4;
  for (int i = tid; i < 1152; i += 256) s_p[i] = pillars[pb * 288 + i];
  float w[9];
#pragma unroll
  for (int d = 0; d < 9; ++d) w[d] = lin_w[c * 9 + d];
  float bl = lin_b[c];
  float sc = ss[c], sh = ss[c + 64];
  __syncthreads();
  const float* pp = &s_p[pe * 288];
  float m = -1e30f;
#pragma unroll 4
  for (int n = 0; n < 32; ++n) {
    float y = bl;
#pragma unroll
    for (int d = 0; d < 9; ++d) y += pp[n * 9 + d] * w[d];
    float v = fmaxf(y * sc + sh, 0.f);
    m = fmaxf(m, v);
  }
  feats[(pb + pe) * 64 + c] = m;
}

// ------------------------------------------------------------------
// Scatter into padded bf16 HWC canvas (numpy last-write-wins)
// ------------------------------------------------------------------

__global__ void scatter_winner(const int* __restrict__ coords, int* __restrict__ winner,
                               int P) {
  int p = blockIdx.x * 256 + threadIdx.x;
  if (p >= P) return;
  int y = coords[p * 3 + 1], x = coords[p * 3 + 2];
  if (y >= 0 && y < 666 && x >= 0 && x < 666) atomicMax(&winner[y * 666 + x], p);
}

__global__ void scatter_img(const int* __restrict__ coords, const int* __restrict__ winner,
                            const float* __restrict__ feats, ushort_t* __restrict__ img,
                            int P, int PW) {
  int idx = blockIdx.x * 256 + threadIdx.x;
  int p = idx >> 6, c = idx & 63;
  if (p >= P) return;
  int y = coords[p * 3 + 1], x = coords[p * 3 + 2];
  if (y >= 0 && y < 666 && x >= 0 && x < 666) {
    if (winner[y * 666 + x] == p)
      img[((size_t)(y + 1) * PW + (x + 1)) * 64 + c] = f2bf(feats[p * 64 + c]);
  }
}

// ------------------------------------------------------------------
// Weight prep: OIHW fp32 -> fragment-ordered bf16 (Kc=32 layout)
// layout: [cc32][pos][s(2)][ntg][lane 64][8]
//   lane l: n = ntg*32 + (l&31); c = cc*32 + s*16 + (l>>5)*8 + j
// ------------------------------------------------------------------

__global__ void prep_w(const float* __restrict__ w, ushort_t* __restrict__ w2, int C,
                       int N, int Ntg, int chunks) {
  int u = blockIdx.x * 256 + threadIdx.x;
  int total = chunks * 9 * 2 * Ntg * 64;
  if (u >= total) return;
  int l = u & 63;
  int g = u >> 6;
  int ntg = g % Ntg;
  int g2 = g / Ntg;
  int s = g2 & 1;
  int g3 = g2 >> 1;
  int pos = g3 % 9;
  int cc = g3 / 9;
  int n = ntg * 32 + (l & 31);
  int c0 = cc * 32 + s * 16 + (l >> 5) * 8;
  ushort_t o8[8];
#pragma unroll
  for (int j = 0; j < 8; ++j) {
    int c = c0 + j;
    float v = (n < N && c < C) ? w[((size_t)n * C + c) * 9 + pos] : 0.f;
    o8[j] = f2bf(v);
  }
  *(uint4*)&w2[(size_t)u * 8] = *(const uint4*)o8;
}

// merged heads: n<21 -> hb_w, 21..23 -> hc_w, >=24 -> 0.  C=256, Ntg=1, chunks=8
__global__ void prep_w_head(const float* __restrict__ hb, const float* __restrict__ hc,
                            ushort_t* __restrict__ w2) {
  int u = blockIdx.x * 256 + threadIdx.x;
  int total = 8 * 9 * 2 * 64;
  if (u >= total) return;
  int l = u & 63;
  int g = u >> 6;
  int s = g & 1;
  int g3 = g >> 1;
  int pos = g3 % 9;
  int cc = g3 / 9;
  int n = l & 31;
  int c0 = cc * 32 + s * 16 + (l >> 5) * 8;
  ushort_t o8[8];
#pragma unroll
  for (int j = 0; j < 8; ++j) {
    int c = c0 + j;
    float v = 0.f;
    if (n < 21) v = hb[((size_t)n * 256 + c) * 9 + pos];
    else if (n < 24) v = hc[((size_t)(n - 21) * 256 + c) * 9 + pos];
    o8[j] = f2bf(v);
  }
  *(uint4*)&w2[(size_t)u * 8] = *(const uint4*)o8;
}

// ------------------------------------------------------------------
// Implicit-GEMM 3x3 conv via v_mfma_f32_32x32x16_bf16.
// Block = 8 waves (512 thr). Tile 64 px x 8 rows, NT*32 oc per block.
// K chunked by 32 ch; per chunk stage input 10x66x32 (xor-swizzled) + weights.
// LDS: 42240 + 18432*NT = 79104 B (NT=2) -> 2 blocks/CU = 16 waves/CU.
// HEAD: blockIdx.z = K-split, atomic epilogue.  STATS: fused BN stats.
// ------------------------------------------------------------------

template <int NT, bool HEAD, bool STATS>
__global__ __launch_bounds__(512, 4) void conv_mfma(
    const ushort_t* __restrict__ in, const ushort_t* __restrict__ w2,
    const float* __restrict__ bias, const float* __restrict__ bias2,
    ushort_t* __restrict__ obf, float* __restrict__ oba, float* __restrict__ obb,
    float* __restrict__ statacc, int PW, int W, int H, int C, int nchunks, int Ntg) {
  __shared__ ushort_t s_in[10 * 66 * 32];           // 42240 B
  __shared__ ushort_t s_w[9 * 2 * NT * 512];        // 18432*NT B
  const int tid = threadIdx.x;
  const int lane = tid & 63, wv = tid >> 6;
  const int lc = lane & 31, lh = lane >> 5;
  const int x0 = blockIdx.x * 64, y0 = blockIdx.y * 8;
  const int z = blockIdx.z;
  const int cc0 = HEAD ? z * nchunks : 0;
  const int z_oc = HEAD ? 0 : z;

  // per-lane A-address precompute
  int pc[2][2][3];
#pragma unroll
  for (int s = 0; s < 2; ++s)
#pragma unroll
    for (int Mt = 0; Mt < 2; ++Mt)
#pragma unroll
      for (int kx = 0; kx < 3; ++kx) {
        int col = Mt * 32 + kx + lc;
        int q = (2 * s + lh) ^ ((col >> 1) & 3);
        pc[s][Mt][kx] = col * 32 + q * 8;
      }

  float bv[NT];
#pragma unroll
  for (int nt = 0; nt < NT; ++nt) {
    if (HEAD) {
      bv[nt] = (z == 0) ? (lc < 21 ? bias[lc] : (lc < 24 ? bias2[lc - 21] : 0.f)) : 0.f;
    } else {
      bv[nt] = bias[(z * NT + nt) * 32 + lc];
    }
  }
  float16 acc[2][NT];
#pragma unroll
  for (int Mt = 0; Mt < 2; ++Mt)
#pragma unroll
    for (int nt = 0; nt < NT; ++nt)
#pragma unroll
      for (int r = 0; r < 16; ++r) acc[Mt][nt][r] = bv[nt];

  const ushort_t* inbase = in + ((size_t)y0 * PW + x0) * C;
  for (int cc = 0; cc < nchunks; ++cc) {
    const int ccg = cc0 + cc;
    __syncthreads();
    // stage input chunk: 10 rows x 66 cols x 4 groups of 8ch (16 B units)
    for (int u = tid; u < 2640; u += 512) {
      int r = u / 264;
      int sr = u - r * 264;
      int col = sr >> 2, f = sr & 3;
      int g = f ^ ((col >> 1) & 3);
      const ushort_t* src = inbase + ((size_t)r * PW + col) * C + ccg * 32 + g * 8;
      *(uint4*)&s_in[(r * 66 + col) * 32 + f * 8] = *(const uint4*)src;
    }
    // stage weight slice: [pos*2+s][nt] x 64 lanes x 16 B
    const int NW = NT * 1152;
    for (int u = tid; u < NW; u += 512) {
      int l16 = u & 63, grp = u >> 6;
      int nt = grp % NT, ps = grp / NT;
      const ushort_t* src =
          w2 + ((size_t)((ccg * 18 + ps) * Ntg + z_oc * NT + nt) * 64 + l16) * 8;
      *(uint4*)&s_w[(size_t)u * 8] = *(const uint4*)src;
    }
    __syncthreads();
#pragma unroll
    for (int ky = 0; ky < 3; ++ky) {
      int rowoff = (wv + ky) * (66 * 32);
#pragma unroll
      for (int kx = 0; kx < 3; ++kx) {
        const int pos = ky * 3 + kx;
#pragma unroll
        for (int s = 0; s < 2; ++s) {
          short8 Bf[NT];
#pragma unroll
          for (int nt = 0; nt < NT; ++nt)
            Bf[nt] = *(const short8*)&s_w[((pos * 2 + s) * NT + nt) * 512 + lane * 8];
#pragma unroll
          for (int Mt = 0; Mt < 2; ++Mt) {
            short8 Af = *(const short8*)&s_in[rowoff + pc[s][Mt][kx]];
#pragma unroll
            for (int nt = 0; nt < NT; ++nt)
              acc[Mt][nt] =
                  __builtin_amdgcn_mfma_f32_32x32x16_bf16(Af, Bf[nt], acc[Mt][nt], 0, 0, 0);
          }
        }
      }
    }
  }

  // ---- epilogue ----
  const int y = y0 + wv;
  const bool yok = (y < H);
  if (HEAD) {
    if (yok) {
#pragma unroll
      for (int Mt = 0; Mt < 2; ++Mt)
#pragma unroll
        for (int r = 0; r < 16; ++r) {
          int m = (r & 3) + 8 * (r >> 2) + 4 * lh;
          int x = x0 + Mt * 32 + m;
          if (x < W) {
            size_t sp = (size_t)y * W + x;
            float v = acc[Mt][0][r];
            if (lc < 21) atomicAdd(&oba[(size_t)lc * (size_t)(H * W) + sp], v);
            else if (lc < 24) atomicAdd(&obb[(size_t)(lc - 21) * (size_t)(H * W) + sp], v);
          }
        }
    }
    return;
  }

  const int Ntot = Ntg * 32;
  if (yok) {
#pragma unroll
    for (int Mt = 0; Mt < 2; ++Mt)
#pragma unroll
      for (int r = 0; r < 16; ++r) {
        int m = (r & 3) + 8 * (r >> 2) + 4 * lh;
        int x = x0 + Mt * 32 + m;
        if (x < W) {
          size_t sp = (size_t)y * W + x;
#pragma unroll
          for (int nt = 0; nt < NT; ++nt) {
            int oc = (z * NT + nt) * 32 + lc;
            obf[sp * Ntot + oc] = f2bf(acc[Mt][nt][r]);
          }
        }
      }
  }

  if (STATS) {
    float s1[NT], s2[NT];
#pragma unroll
    for (int nt = 0; nt < NT; ++nt) { s1[nt] = 0.f; s2[nt] = 0.f; }
    if (yok) {
#pragma unroll
      for (int Mt = 0; Mt < 2; ++Mt)
#pragma unroll
        for (int r = 0; r < 16; ++r) {
          int m = (r & 3) + 8 * (r >> 2) + 4 * lh;
          int x = x0 + Mt * 32 + m;
          if (x < W) {
#pragma unroll
            for (int nt = 0; nt < NT; ++nt) {
              float v = acc[Mt][nt][r];
              s1[nt] += v;
              s2[nt] += v * v;
            }
          }
        }
    }
#pragma unroll
    for (int nt = 0; nt < NT; ++nt) {
      s1[nt] += __shfl_xor(s1[nt], 32);
      s2[nt] += __shfl_xor(s2[nt], 32);
    }
    __syncthreads();  // all MFMA LDS reads done; reuse s_in as fp32 scratch
    float* red = (float*)s_in;
    if (lh == 0) {
#pragma unroll
      for (int nt = 0; nt < NT; ++nt) {
        red[(wv * NT + nt) * 32 + lc] = s1[nt];
        red[8 * NT * 32 + (wv * NT + nt) * 32 + lc] = s2[nt];
      }
    }
    __syncthreads();
    if (wv == 0 && lh == 0) {
#pragma unroll
      for (int nt = 0; nt < NT; ++nt) {
        float a = 0.f, b = 0.f;
#pragma unroll
        for (int w8 = 0; w8 < 8; ++w8) {
          a += red[(w8 * NT + nt) * 32 + lc];
          b += red[8 * NT * 32 + (w8 * NT + nt) * 32 + lc];
        }
        int ch = (z * NT + nt) * 32 + lc;
        atomicAdd(&statacc[ch], a);
        atomicAdd(&statacc[ch + 256], b);
      }
    }
  }
}

// ------------------------------------------------------------------
// Fused BN-finalize + elementwise (4 channels / thread, natural order).
// Scale/shift computed on the fly from stats accumulators.
// ------------------------------------------------------------------

__device__ __forceinline__ float bnrl(ushort_t u, float sc, float sh) {
  return fmaxf(bf2f(u) * sc + sh, 0.f);
}

__device__ __forceinline__ void bn_coefs(const float* acc, const float* g,
                                         const float* b, int c, float invN, float4& sc,
                                         float4& sh) {
  float4 s1 = *(const float4*)&acc[c];
  float4 s2 = *(const float4*)&acc[c + 256];
  float4 gv = *(const float4*)&g[c];
  float4 bv = *(const float4*)&b[c];
  float m, v;
  m = s1.x * invN; v = fmaxf(s2.x * invN - m * m, 0.f);
  sc.x = gv.x * rsqrtf(v + BN_EPS); sh.x = bv.x - m * sc.x;
  m = s1.y * invN; v = fmaxf(s2.y * invN - m * m, 0.f);
  sc.y = gv.y * rsqrtf(v + BN_EPS); sh.y = bv.y - m * sc.y;
  m = s1.z * invN; v = fmaxf(s2.z * invN - m * m, 0.f);
  sc.z = gv.z * rsqrtf(v + BN_EPS); sh.z = bv.z - m * sc.z;
  m = s1.w * invN; v = fmaxf(s2.w * invN - m * m, 0.f);
  sc.w = gv.w * rsqrtf(v + BN_EPS); sh.w = bv.w - m * sc.w;
}

// BN+relu+2x2pool from bf16 HWC (Wi wide) into padded bf16 HWC (PWo pitch)
__global__ __launch_bounds__(256) void bn_relu_pool_pad4(
    const ushort_t* __restrict__ in, const float* __restrict__ acc,
    const float* __restrict__ g, const float* __restrict__ b, float invN,
    ushort_t* __restrict__ out, int Wi, int OW, int OH, int C, int cshift2, int PWo) {
  int idx = blockIdx.x * 256 + threadIdx.x;
  int total = OH * OW * (C >> 2);
  if (idx >= total) return;
  int cq = idx & ((C >> 2) - 1);
  int p = idx >> cshift2;
  int ox = p % OW;
  int oy = p / OW;
  int c = cq << 2;
  float4 scv, shv;
  bn_coefs(acc, g, b, c, invN, scv, shv);
  const ushort_t* ip = in + ((size_t)(2 * oy) * Wi + 2 * ox) * C + c;
  ushort4 a0 = *(const ushort4*)(ip);
  ushort4 a1 = *(const ushort4*)(ip + C);
  ushort4 a2 = *(const ushort4*)(ip + (size_t)Wi * C);
  ushort4 a3 = *(const ushort4*)(ip + (size_t)Wi * C + C);
  ushort4 o;
  o.x = f2bf(fmaxf(fmaxf(bnrl(a0.x, scv.x, shv.x), bnrl(a1.x, scv.x, shv.x)),
                   fmaxf(bnrl(a2.x, scv.x, shv.x), bnrl(a3.x, scv.x, shv.x))));
  o.y = f2bf(fmaxf(fmaxf(bnrl(a0.y, scv.y, shv.y), bnrl(a1.y, scv.y, shv.y)),
                   fmaxf(bnrl(a2.y, scv.y, shv.y), bnrl(a3.y, scv.y, shv.y))));
  o.z = f2bf(fmaxf(fmaxf(bnrl(a0.z, scv.z, shv.z), bnrl(a1.z, scv.z, shv.z)),
                   fmaxf(bnrl(a2.z, scv.z, shv.z), bnrl(a3.z, scv.z, shv.z))));
  o.w = f2bf(fmaxf(fmaxf(bnrl(a0.w, scv.w, shv.w), bnrl(a1.w, scv.w, shv.w)),
                   fmaxf(bnrl(a2.w, scv.w, shv.w), bnrl(a3.w, scv.w, shv.w))));
  *(ushort4*)&out[((size_t)(oy + 1) * PWo + (ox + 1)) * C + c] = o;
}

// BN+relu (no pool) from bf16 HWC into padded bf16 HWC
__global__ __launch_bounds__(256) void bn_relu_pad4(
    const ushort_t* __restrict__ in, const float* __restrict__ acc,
    const float* __restrict__ g, const float* __restrict__ b, float invN,
    ushort_t* __restrict__ out, int Wi, int C, int cshift2, int PWo) {
  int idx = blockIdx.x * 256 + threadIdx.x;
  int total = Wi * Wi * (C >> 2);
  if (idx >= total) return;
  int cq = idx & ((C >> 2) - 1);
  int p = idx >> cshift2;
  int x = p % Wi;
  int y = p / Wi;
  int c = cq << 2;
  float4 scv, shv;
  bn_coefs(acc, g, b, c, invN, scv, shv);
  ushort4 a = *(const ushort4*)&in[(size_t)p * C + c];
  ushort4 o;
  o.x = f2bf(bnrl(a.x, scv.x, shv.x));
  o.y = f2bf(bnrl(a.y, scv.y, shv.y));
  o.z = f2bf(bnrl(a.z, scv.z, shv.z));
  o.w = f2bf(bnrl(a.w, scv.w, shv.w));
  *(ushort4*)&out[((size_t)(y + 1) * PWo + (x + 1)) * C + c] = o;
}

// ------------------------------------------------------------------

extern "C" void kernel_launch(void* const* d_in, const int* in_sizes, int n_in,
                              void* d_out, int out_size, void* d_ws, size_t ws_size,
                              hipStream_t stream) {
  (void)in_sizes; (void)n_in; (void)out_size; (void)ws_size;
  const float* pillars = (const float*)d_in[0];
  const int* coords = (const int*)d_in[1];
  const float* lin_w = (const float*)d_in[2];
  const float* lin_b = (const float*)d_in[3];
  const float* pfn_g = (const float*)d_in[4];
  const float* pfn_b = (const float*)d_in[5];
  const float* c1_w = (const float*)d_in[6];
  const float* c1_b = (const float*)d_in[7];
  const float* bn1_g = (const float*)d_in[8];
  const float* bn1_b = (const float*)d_in[9];
  const float* c2_w = (const float*)d_in[10];
  const float* c2_b = (const float*)d_in[11];
  const float* bn2_g = (const float*)d_in[12];
  const float* bn2_b = (const float*)d_in[13];
  const float* h1_w = (const float*)d_in[14];
  const float* h1_b = (const float*)d_in[15];
  const float* hbn_g = (const float*)d_in[16];
  const float* hbn_b = (const float*)d_in[17];
  const float* hb_w = (const float*)d_in[18];
  const float* hb_b = (const float*)d_in[19];
  const float* hc_w = (const float*)d_in[20];
  const float* hc_b = (const float*)d_in[21];
  float* out = (float*)d_out;

  // ---- workspace layout (bytes) ----
  char* ws = (char*)d_ws;
  float* pfn_acc = (float*)(ws + 0);         // 512 B
  float* pfn_ss  = (float*)(ws + 512);       // 512 B
  float* bn_acc1 = (float*)(ws + 1024);      // 2048 B
  float* bn_acc2 = (float*)(ws + 3072);      // 2048 B
  float* bn_acc3 = (float*)(ws + 5120);      // 2048 B
  int* winner    = (int*)(ws + 7168);        // 1774224 B
  float* feats   = (float*)(ws + 1781760);   // 5120000 B
  ushort_t* canvas = (ushort_t*)(ws + 6902272);     // 706x674x64   = 60899328 B
  ushort_t* c1out  = (ushort_t*)(ws + 67801600);    // 666x666x64   = 56775168 B
  ushort_t* c2in   = (ushort_t*)(ws + 124576768);   // 386x338x64   = 16699904 B
  ushort_t* c2out  = (ushort_t*)(ws + 141276672);   // 333x333x128  = 28387584 B
  ushort_t* h1in   = (ushort_t*)(ws + 169664256);   // 194x170x128  = 8442880 B
  ushort_t* h1out  = (ushort_t*)(ws + 178107136);   // 166x166x256  = 14108672 B
  ushort_t* hdin   = (ushort_t*)(ws + 192215808);   // 194x170x256  = 16885760 B
  ushort_t* w2c1   = (ushort_t*)(ws + 209101568);   // 73728 B
  ushort_t* w2c2   = (ushort_t*)(ws + 209175296);   // 147456 B
  ushort_t* w2h1   = (ushort_t*)(ws + 209322752);   // 589824 B
  ushort_t* w2hd   = (ushort_t*)(ws + 209912576);   // 147456 B

  const int HW3 = 166 * 166;

  // ---- upfront zero-init ----
  hipMemsetAsync(ws, 0, 7168, stream);  // pfn_acc/pfn_ss/bn_acc1-3
  hipMemsetAsync(winner, 0xFF, 1774224, stream);
  hipMemsetAsync(canvas, 0, 60899328, stream);
  hipMemsetAsync(c2in, 0, 16699904, stream);
  hipMemsetAsync(h1in, 0, 8442880, stream);
  hipMemsetAsync(hdin, 0, 16885760, stream);
  hipMemsetAsync(out, 0, (size_t)24 * HW3 * 4, stream);  // head accumulates via atomics

  // ---- weight prep (Kc=32 layout) ----
  prep_w<<<18, 256, 0, stream>>>(c1_w, w2c1, 64, 64, 2, 2);
  prep_w<<<36, 256, 0, stream>>>(c2_w, w2c2, 64, 128, 4, 2);
  prep_w<<<144, 256, 0, stream>>>(h1_w, w2h1, 128, 256, 8, 4);
  prep_w_head<<<36, 256, 0, stream>>>(hb_w, hc_w, w2hd);

  // ---- PFN ----
  pfn_stats<<<625, 256, 0, stream>>>(pillars, lin_w, lin_b, pfn_acc);
  pfn_finalize<<<1, 64, 0, stream>>>(pfn_acc, pfn_g, pfn_b, pfn_ss);
  pfn_feats<<<5000, 256, 0, stream>>>(pillars, lin_w, lin_b, pfn_ss, feats);

  // ---- scatter ----
  scatter_winner<<<(20000 + 255) / 256, 256, 0, stream>>>(coords, winner, 20000);
  scatter_img<<<5000, 256, 0, stream>>>(coords, winner, feats, canvas, 20000, 706);

  // ---- conv1: 666x666, 64->64, 2 K-chunks (stats fused) ----
  conv_mfma<2, false, true><<<dim3(11, 84, 1), 512, 0, stream>>>(
      canvas, w2c1, c1_b, nullptr, c1out, nullptr, nullptr, bn_acc1, 706, 666, 666, 64,
      2, 2);
  bn_relu_pool_pad4<<<(333 * 333 * 16 + 255) / 256, 256, 0, stream>>>(
      c1out, bn_acc1, bn1_g, bn1_b, 1.f / 443556.f, c2in, 666, 333, 333, 64, 4, 386);

  // ---- conv2: 333x333, 64->128, 2 K-chunks (stats fused) ----
  conv_mfma<2, false, true><<<dim3(6, 42, 2), 512, 0, stream>>>(
      c2in, w2c2, c2_b, nullptr, c2out, nullptr, nullptr, bn_acc2, 386, 333, 333, 64, 2,
      4);
  bn_relu_pool_pad4<<<(166 * 166 * 32 + 255) / 256, 256, 0, stream>>>(
      c2out, bn_acc2, bn2_g, bn2_b, 1.f / 110889.f, h1in, 333, 166, 166, 128, 5, 194);

  // ---- h1: 166x166, 128->256, 4 K-chunks (stats fused) ----
  conv_mfma<2, false, true><<<dim3(3, 21, 4), 512, 0, stream>>>(
      h1in, w2h1, h1_b, nullptr, h1out, nullptr, nullptr, bn_acc3, 194, 166, 166, 128, 4,
      8);
  bn_relu_pad4<<<(HW3 * 64 + 255) / 256, 256, 0, stream>>>(
      h1out, bn_acc3, hbn_g, hbn_b, 1.f / 27556.f, hdin, 166, 256, 6, 194);

  // ---- heads: 166x166, 256->(21+3), K-split z=2 (4 chunks each), atomics ----
  conv_mfma<1, true, false><<<dim3(3, 21, 2), 512, 0, stream>>>(
      hdin, w2hd, hb_b, hc_b, nullptr, out, out + (size_t)21 * HW3, nullptr, 194, 166,
      166, 256, 4, 1);
}